// Round 12
// baseline (245.896 us; speedup 1.0000x reference)
//
#include <hip/hip_runtime.h>
#include <math.h>

#define BB 16
#define SS 256
#define FF 512
#define EE 128
#define HH 64
#define GG 192  // 3H
#define LL 8
#define TT 16   // scan tile count (SS/16)

__device__ __forceinline__ float sigmoid_f(float x) {
    return 1.0f / (1.0f + __expf(-x));
}
__device__ __forceinline__ float tanh_f(float x) {
    return 1.0f - 2.0f / (1.0f + __expf(2.0f * x));
}

// ---------------------------------------------------------------------------
// Generic C[m,n] = sum_k A[m,k] * Bm[n,k] + bias[n]
// ---------------------------------------------------------------------------
__device__ __forceinline__ void gemm_bt_body(
    const float* __restrict__ A, const float* __restrict__ Bm,
    const float* __restrict__ bias, float* __restrict__ C,
    int N, int K)
{
    __shared__ float As[32][68];
    __shared__ float Bs[64][68];
    const int t = threadIdx.x;
    const int row0 = blockIdx.x * 32;
    const int col0 = blockIdx.y * 64;
    const int tr = t & 7;
    const int tc = t >> 3;
    float acc[4][2] = {{0.f,0.f},{0.f,0.f},{0.f,0.f},{0.f,0.f}};

    for (int k0 = 0; k0 < K; k0 += 64) {
        {
            int r = t >> 3;
            int q = t & 7;
            const float* src = &A[(size_t)(row0 + r) * K + k0];
            #pragma unroll
            for (int it = 0; it < 2; ++it) {
                int kk = (q + it * 8) * 4;
                *(float4*)&As[r][kk] = *(const float4*)&src[kk];
            }
        }
        {
            int r = t >> 2;
            int q = t & 3;
            int n = col0 + r;
            #pragma unroll
            for (int it = 0; it < 4; ++it) {
                int kk = (q + it * 4) * 4;
                float4 v = {0.f, 0.f, 0.f, 0.f};
                if (n < N) v = *(const float4*)&Bm[(size_t)n * K + k0 + kk];
                *(float4*)&Bs[r][kk] = v;
            }
        }
        __syncthreads();
        #pragma unroll
        for (int k = 0; k < 64; k += 4) {
            float4 av[4], bv[2];
            #pragma unroll
            for (int i = 0; i < 4; ++i) av[i] = *(const float4*)&As[tr + 8*i][k];
            #pragma unroll
            for (int j = 0; j < 2; ++j) bv[j] = *(const float4*)&Bs[tc + 32*j][k];
            #pragma unroll
            for (int i = 0; i < 4; ++i)
                #pragma unroll
                for (int j = 0; j < 2; ++j)
                    acc[i][j] += av[i].x*bv[j].x + av[i].y*bv[j].y
                               + av[i].z*bv[j].z + av[i].w*bv[j].w;
        }
        __syncthreads();
    }

    #pragma unroll
    for (int i = 0; i < 4; ++i) {
        int r = row0 + tr + 8*i;
        #pragma unroll
        for (int j = 0; j < 2; ++j) {
            int c = col0 + tc + 32*j;
            if (c < N) C[(size_t)r * N + c] = acc[i][j] + bias[c];
        }
    }
}

__global__ __launch_bounds__(256) void gemm_bt(
    const float* __restrict__ A, const float* __restrict__ Bm,
    const float* __restrict__ bias, float* __restrict__ C,
    int N, int K)
{
    gemm_bt_body(A, Bm, bias, C, N, K);
}

__global__ __launch_bounds__(256) void gemm_bt_dual(
    const float* __restrict__ A,
    const float* __restrict__ B0, const float* __restrict__ bias0, float* __restrict__ C0,
    const float* __restrict__ B1, const float* __restrict__ bias1, float* __restrict__ C1,
    int N, int K)
{
    const float* Bm   = blockIdx.z ? B1    : B0;
    const float* bias = blockIdx.z ? bias1 : bias0;
    float*       C    = blockIdx.z ? C1    : C0;
    gemm_bt_body(A, Bm, bias, C, N, K);
}

// ---------------------------------------------------------------------------
// GRU scan (r12). 3-wave structure from r7/r10 (one gate per wave, lgkm-only
// barrier, double-buffered gh). WEIGHTS NOW LIVE IN LDS — verdict after
// r2-r11: the RA refuses to keep 64 weight floats live across this loop
// (scratch via rule #20, or invariant-load remat; pin regressed). So let it
// re-fetch per step, but from LDS (~120cyc pipelined, conflict-free) instead
// of L2 (~350cyc). Staged once (192 threads x 1 row). Layout: [192][64] f32
// with XOR-swizzled 16B chunks (chunk' = c ^ (row&15)): lanes 0-15 hit 16
// distinct 16B slots -> each bank exactly 2x per quarter wave -> conflict-
// free ds_read_b128 (plain row-major would be 8-way). The in-loop barrier +
// asm memory clobbers prevent hoisting the (loop-invariant) LDS reads, so
// there is no register-pressure path back to the old failure mode.
// ---------------------------------------------------------------------------
__global__ __launch_bounds__(192, 1)
__attribute__((amdgpu_waves_per_eu(1, 1)))
void gru_kernel(
    const float* __restrict__ xpa, const float* __restrict__ xpb,
    const float* __restrict__ Whh_a, const float* __restrict__ bhh_a,
    const float* __restrict__ Whh_b, const float* __restrict__ bhh_b,
    float* __restrict__ hs_a, float* __restrict__ hs_b)
{
    const int blk = blockIdx.x;
    const int b = blk >> 1;
    const int which = blk & 1;
    const float* xp  = which ? xpb   : xpa;
    const float* Whh = which ? Whh_b : Whh_a;
    const float* bhh = which ? bhh_b : bhh_a;
    float* hs        = which ? hs_b  : hs_a;

    const int t = threadIdx.x;       // 0..191
    const int g = t >> 6;            // gate: 0=r, 1=z, 2=n
    const int j = t & 63;

    __shared__ float w_lds[GG * HH]; // 48 KB, swizzled
    __shared__ float gh_s[2][GG];

    // Stage this thread's weight row into LDS (swizzled 16B chunks).
    {
        const float4* wrow = (const float4*)&Whh[(size_t)t * HH];
        const int base = t * HH;
        const int swz = t & 15;
        #pragma unroll
        for (int c = 0; c < 16; ++c) {
            *(float4*)&w_lds[base + ((c ^ swz) << 2)] = wrow[c];
        }
    }
    const float bh = bhh[t];
    __syncthreads();

    const float* xrow = xp + (size_t)b * SS * GG;
    float* hrow = hs + (size_t)b * SS * HH;
    float hcur = 0.f;

    float xg = xrow[t];              // own-gate x (t = g*64+j)
    float xn = xrow[128 + j];

    const int wbase = t * HH;
    const int wswz = t & 15;

#define RL(v, k) __int_as_float(__builtin_amdgcn_readlane(__float_as_int(v), (k)))

    for (int s = 0; s < SS; ++s) {
        // Prefetch next step's xp (stays in flight across the lgkm-only
        // barrier; last iter reads past the array into adjacent workspace —
        // harmless, value discarded).
        const float* nx = xrow + GG;
        float nxg = nx[t];
        float nxn = nx[128 + j];

        // own-gate dot: bh + W[row] . h, weights streamed from LDS
        float a0 = bh, a1 = 0.f, a2 = 0.f, a3 = 0.f;
        #pragma unroll
        for (int c = 0; c < 16; ++c) {
            float4 wk = *(const float4*)&w_lds[wbase + ((c ^ wswz) << 2)];
            a0 = fmaf(wk.x, RL(hcur, 4*c + 0), a0);
            a1 = fmaf(wk.y, RL(hcur, 4*c + 1), a1);
            a2 = fmaf(wk.z, RL(hcur, 4*c + 2), a2);
            a3 = fmaf(wk.w, RL(hcur, 4*c + 3), a3);
        }
        float pre = (a0 + a1) + (a2 + a3);
        gh_s[s & 1][t] = (g < 2) ? (xg + pre) : pre;

        // LDS-only barrier: don't drain vmcnt.
        asm volatile("s_waitcnt lgkmcnt(0)" ::: "memory");
        __builtin_amdgcn_s_barrier();
        asm volatile("" ::: "memory");

        float ghr = gh_s[s & 1][j];
        float ghz = gh_s[s & 1][64 + j];
        float ghn = gh_s[s & 1][128 + j];
        float r = sigmoid_f(ghr);
        float z = sigmoid_f(ghz);
        float n = tanh_f(xn + r * ghn);
        hcur = fmaf(z, hcur - n, n);
        if (g == 0) hrow[j] = hcur;

        xg = nxg; xn = nxn;
        xrow += GG;
        hrow += HH;
    }
#undef RL
}

// ---------------------------------------------------------------------------
// Per (b,j): wj = exp(h_alpha . Wa + ba) * M;  val[e] = tanh(h_beta . Wb[e] + bb[e]) * emb[e] * wj
// ---------------------------------------------------------------------------
__global__ __launch_bounds__(128) void attn_val_kernel(
    const float* __restrict__ h_alpha, const float* __restrict__ h_beta,
    const float* __restrict__ emb, const float* __restrict__ M,
    const float* __restrict__ Wa, const float* __restrict__ ba,
    const float* __restrict__ Wb, const float* __restrict__ bb,
    float* __restrict__ val, float* __restrict__ wj)
{
    const int bj = blockIdx.x;
    const int t = threadIdx.x;
    __shared__ float hb_s[HH];
    __shared__ float wj_s;

    if (t < 64) {
        hb_s[t] = h_beta[(size_t)bj * HH + t];
        float p = h_alpha[(size_t)bj * HH + t] * Wa[t];
        #pragma unroll
        for (int off = 32; off > 0; off >>= 1) p += __shfl_down(p, off);
        if (t == 0) {
            float a = __expf(p + ba[0]) * M[bj];
            wj_s = a;
            wj[bj] = a;
        }
    }
    __syncthreads();

    float acc = bb[t];
    const float4* wrow = (const float4*)&Wb[(size_t)t * HH];
    #pragma unroll
    for (int k = 0; k < 16; ++k) {
        float4 w4 = wrow[k];
        float4 h4 = *(const float4*)&hb_s[k * 4];
        acc += w4.x*h4.x + w4.y*h4.y + w4.z*h4.z + w4.w*h4.w;
    }
    float bw = tanh_f(acc);
    val[(size_t)bj * EE + t] = bw * emb[(size_t)bj * EE + t] * wj_s;
}

// ---------------------------------------------------------------------------
// Suffix scan, two-level parallel: scanA tile sums, scanB suffix.
// ---------------------------------------------------------------------------
__global__ __launch_bounds__(128) void scanA_kernel(
    const float* __restrict__ val, const float* __restrict__ wj,
    float* __restrict__ tsum, float* __restrict__ wsum)
{
    const int b = blockIdx.x, tt = blockIdx.y;
    const int e = threadIdx.x;
    const int j0 = tt * 16;
    float s = 0.f;
    #pragma unroll
    for (int jj = 0; jj < 16; ++jj)
        s += val[((size_t)(b * SS + j0 + jj)) * EE + e];
    tsum[((size_t)(b * TT + tt)) * EE + e] = s;

    if (e < 16) {
        float p = wj[b * SS + j0 + e];
        #pragma unroll
        for (int off = 8; off > 0; off >>= 1) p += __shfl_down(p, off, 16);
        if (e == 0) wsum[b * TT + tt] = p;
    }
}

__global__ __launch_bounds__(128) void scanB_kernel(
    const float* __restrict__ val, const float* __restrict__ wj,
    const float* __restrict__ tsum, const float* __restrict__ wsum,
    float* __restrict__ wtd)
{
    const int b = blockIdx.x, tt = blockIdx.y;
    const int e = threadIdx.x;
    const int j0 = tt * 16;

    float se = 0.f;
    for (int t2 = tt + 1; t2 < TT; ++t2)
        se += tsum[((size_t)(b * TT + t2)) * EE + e];
    float d = 1e-10f;
    for (int t2 = tt + 1; t2 < TT; ++t2)
        d += wsum[b * TT + t2];

    for (int jj = 15; jj >= 0; --jj) {
        size_t idx = ((size_t)(b * SS + j0 + jj)) * EE + e;
        se += val[idx];
        d += wj[b * SS + j0 + jj];
        wtd[idx] = se / d;
    }
}

// ---------------------------------------------------------------------------
// all_output[b,s,l] = (weighted[b,s,:] . Wp[l,:] + bp[l]) * M[b,s]
// ---------------------------------------------------------------------------
__global__ __launch_bounds__(256) void proj_kernel(
    const float* __restrict__ wtd, const float* __restrict__ Wp,
    const float* __restrict__ bp, const float* __restrict__ M,
    float* __restrict__ out)
{
    __shared__ float wt_s[32][132];
    __shared__ float wp_s[8][132];
    const int t = threadIdx.x;
    const int row0 = blockIdx.x * 32;

    {
        int r = t >> 3;
        int q = t & 7;
        const float* src = &wtd[(size_t)(row0 + r) * EE];
        #pragma unroll
        for (int it = 0; it < 4; ++it) {
            int kk = (q + it * 8) * 4;
            *(float4*)&wt_s[r][kk] = *(const float4*)&src[kk];
        }
    }
    {
        int r = t >> 5;
        int q = t & 31;
        *(float4*)&wp_s[r][q * 4] = *(const float4*)&Wp[(size_t)r * EE + q * 4];
    }
    __syncthreads();

    const int r = t >> 3, l = t & 7;
    float acc = 0.f;
    #pragma unroll
    for (int i = 0; i < 32; ++i) {
        float4 a = *(const float4*)&wt_s[r][i * 4];
        float4 w = *(const float4*)&wp_s[l][i * 4];
        acc += a.x*w.x + a.y*w.y + a.z*w.z + a.w*w.w;
    }
    const int row = row0 + r;
    out[(size_t)row * LL + l] = (acc + bp[l]) * M[row];
}

// ---------------------------------------------------------------------------
// cur_output[b,l] = sum_s all_output[b,s,l] * cur_M[b,s]
// ---------------------------------------------------------------------------
__global__ __launch_bounds__(256) void cur_kernel(
    const float* __restrict__ out_all, const float* __restrict__ curM,
    float* __restrict__ out_cur)
{
    const int b = blockIdx.x;
    const int t = threadIdx.x;
    const int l = t & 7, c = t >> 3;
    float p = 0.f;
    #pragma unroll
    for (int k = 0; k < 8; ++k) {
        int s = c + k * 32;
        p += out_all[((size_t)(b * SS + s)) * LL + l] * curM[b * SS + s];
    }
    __shared__ float red[32][9];
    red[c][l] = p;
    __syncthreads();
    if (t < 8) {
        float sum = 0.f;
        for (int c2 = 0; c2 < 32; ++c2) sum += red[c2][t];
        out_cur[b * LL + t] = sum;
    }
}

// ---------------------------------------------------------------------------
extern "C" void kernel_launch(void* const* d_in, const int* in_sizes, int n_in,
                              void* d_out, int out_size, void* d_ws, size_t ws_size,
                              hipStream_t stream)
{
    const float* X       = (const float*)d_in[0];
    const float* M       = (const float*)d_in[1];
    const float* cur_M   = (const float*)d_in[2];
    const float* W_embed = (const float*)d_in[3];
    const float* b_embed = (const float*)d_in[4];
    const float* Wih_a   = (const float*)d_in[5];
    const float* Whh_a   = (const float*)d_in[6];
    const float* bih_a   = (const float*)d_in[7];
    const float* bhh_a   = (const float*)d_in[8];
    const float* Wih_b   = (const float*)d_in[9];
    const float* Whh_b   = (const float*)d_in[10];
    const float* bih_b   = (const float*)d_in[11];
    const float* bhh_b   = (const float*)d_in[12];
    const float* Wb      = (const float*)d_in[13];
    const float* bb      = (const float*)d_in[14];
    const float* Wa      = (const float*)d_in[15];
    const float* ba      = (const float*)d_in[16];
    const float* Wp      = (const float*)d_in[17];
    const float* bp      = (const float*)d_in[18];
    float* out = (float*)d_out;

    float* ws  = (float*)d_ws;
    float* emb = ws;                          // B*S*E
    float* xpa = emb + (size_t)BB*SS*EE;      // B*S*192
    float* xpb = xpa + (size_t)BB*SS*GG;
    float* ha  = xpb + (size_t)BB*SS*GG;      // B*S*H
    float* hb  = ha  + (size_t)BB*SS*HH;
    float* val = hb  + (size_t)BB*SS*HH;      // B*S*E
    float* wjv = val + (size_t)BB*SS*EE;      // B*S
    float* wtd = wjv + (size_t)BB*SS;         // B*S*E
    float* tsum = wtd + (size_t)BB*SS*EE;     // B*TT*E
    float* wsum = tsum + (size_t)BB*TT*EE;    // B*TT

    const int ROWS = BB * SS;                 // 4096

    gemm_bt<<<dim3(ROWS/32, EE/64), 256, 0, stream>>>(X, W_embed, b_embed, emb, EE, FF);
    gemm_bt_dual<<<dim3(ROWS/32, (GG+63)/64, 2), 256, 0, stream>>>(
        emb, Wih_a, bih_a, xpa, Wih_b, bih_b, xpb, GG, EE);
    gru_kernel<<<32, 192, 0, stream>>>(xpa, xpb, Whh_a, bhh_a, Whh_b, bhh_b, ha, hb);
    attn_val_kernel<<<ROWS, 128, 0, stream>>>(ha, hb, emb, M, Wa, ba, Wb, bb, val, wjv);
    scanA_kernel<<<dim3(BB, TT), 128, 0, stream>>>(val, wjv, tsum, wsum);
    scanB_kernel<<<dim3(BB, TT), 128, 0, stream>>>(val, wjv, tsum, wsum, wtd);
    proj_kernel<<<ROWS/32, 256, 0, stream>>>(wtd, Wp, bp, M, out);
    cur_kernel<<<BB, 256, 0, stream>>>(out, cur_M, out + (size_t)BB*SS*LL);
}

// Round 13
// 172.857 us; speedup vs baseline: 1.4225x; 1.4225x over previous
//
#include <hip/hip_runtime.h>
#include <math.h>

#define BB 16
#define SS 256
#define FF 512
#define EE 128
#define HH 64
#define GG 192  // 3H
#define LL 8
#define TT 16   // scan tile count (SS/16)

__device__ __forceinline__ float sigmoid_f(float x) {
    return 1.0f / (1.0f + __expf(-x));
}
__device__ __forceinline__ float tanh_f(float x) {
    return 1.0f - 2.0f / (1.0f + __expf(2.0f * x));
}

// ---------------------------------------------------------------------------
// Generic C[m,n] = sum_k A[m,k] * Bm[n,k] + bias[n]
// ---------------------------------------------------------------------------
__device__ __forceinline__ void gemm_bt_body(
    const float* __restrict__ A, const float* __restrict__ Bm,
    const float* __restrict__ bias, float* __restrict__ C,
    int N, int K)
{
    __shared__ float As[32][68];
    __shared__ float Bs[64][68];
    const int t = threadIdx.x;
    const int row0 = blockIdx.x * 32;
    const int col0 = blockIdx.y * 64;
    const int tr = t & 7;
    const int tc = t >> 3;
    float acc[4][2] = {{0.f,0.f},{0.f,0.f},{0.f,0.f},{0.f,0.f}};

    for (int k0 = 0; k0 < K; k0 += 64) {
        {
            int r = t >> 3;
            int q = t & 7;
            const float* src = &A[(size_t)(row0 + r) * K + k0];
            #pragma unroll
            for (int it = 0; it < 2; ++it) {
                int kk = (q + it * 8) * 4;
                *(float4*)&As[r][kk] = *(const float4*)&src[kk];
            }
        }
        {
            int r = t >> 2;
            int q = t & 3;
            int n = col0 + r;
            #pragma unroll
            for (int it = 0; it < 4; ++it) {
                int kk = (q + it * 4) * 4;
                float4 v = {0.f, 0.f, 0.f, 0.f};
                if (n < N) v = *(const float4*)&Bm[(size_t)n * K + k0 + kk];
                *(float4*)&Bs[r][kk] = v;
            }
        }
        __syncthreads();
        #pragma unroll
        for (int k = 0; k < 64; k += 4) {
            float4 av[4], bv[2];
            #pragma unroll
            for (int i = 0; i < 4; ++i) av[i] = *(const float4*)&As[tr + 8*i][k];
            #pragma unroll
            for (int j = 0; j < 2; ++j) bv[j] = *(const float4*)&Bs[tc + 32*j][k];
            #pragma unroll
            for (int i = 0; i < 4; ++i)
                #pragma unroll
                for (int j = 0; j < 2; ++j)
                    acc[i][j] += av[i].x*bv[j].x + av[i].y*bv[j].y
                               + av[i].z*bv[j].z + av[i].w*bv[j].w;
        }
        __syncthreads();
    }

    #pragma unroll
    for (int i = 0; i < 4; ++i) {
        int r = row0 + tr + 8*i;
        #pragma unroll
        for (int j = 0; j < 2; ++j) {
            int c = col0 + tc + 32*j;
            if (c < N) C[(size_t)r * N + c] = acc[i][j] + bias[c];
        }
    }
}

__global__ __launch_bounds__(256) void gemm_bt(
    const float* __restrict__ A, const float* __restrict__ Bm,
    const float* __restrict__ bias, float* __restrict__ C,
    int N, int K)
{
    gemm_bt_body(A, Bm, bias, C, N, K);
}

__global__ __launch_bounds__(256) void gemm_bt_dual(
    const float* __restrict__ A,
    const float* __restrict__ B0, const float* __restrict__ bias0, float* __restrict__ C0,
    const float* __restrict__ B1, const float* __restrict__ bias1, float* __restrict__ C1,
    int N, int K)
{
    const float* Bm   = blockIdx.z ? B1    : B0;
    const float* bias = blockIdx.z ? bias1 : bias0;
    float*       C    = blockIdx.z ? C1    : C0;
    gemm_bt_body(A, Bm, bias, C, N, K);
}

// ---------------------------------------------------------------------------
// GRU scan — exact r10 (best known: 108.7us). 3 waves/chain (one gate per
// wave), weights as named float4 SSA (re-fetched from L1/L2 by remat, which
// measured cheaper than scratch r5-r9, pin r11, or LDS r12), lgkm-only
// barrier, double-buffered gh. Verdict of r2-r12: 1019 cyc/step =
// ~350 issue + ~250 load latency + ~150 barrier + ~120 LDS + ~50 gates;
// only an MFMA rewrite changes the structure materially.
// ---------------------------------------------------------------------------
__global__ __launch_bounds__(192, 1)
__attribute__((amdgpu_waves_per_eu(1, 1)))
void gru_kernel(
    const float* __restrict__ xpa, const float* __restrict__ xpb,
    const float* __restrict__ Whh_a, const float* __restrict__ bhh_a,
    const float* __restrict__ Whh_b, const float* __restrict__ bhh_b,
    float* __restrict__ hs_a, float* __restrict__ hs_b)
{
    const int blk = blockIdx.x;
    const int b = blk >> 1;
    const int which = blk & 1;
    const float* xp  = which ? xpb   : xpa;
    const float* Whh = which ? Whh_b : Whh_a;
    const float* bhh = which ? bhh_b : bhh_a;
    float* hs        = which ? hs_b  : hs_a;

    const int t = threadIdx.x;       // 0..191
    const int g = t >> 6;            // gate: 0=r, 1=z, 2=n
    const int j = t & 63;

    __shared__ float gh_s[2][GG];

    const float4* wrow = (const float4*)&Whh[(size_t)(g * 64 + j) * HH];
    float4 w0  = wrow[0],  w1  = wrow[1],  w2  = wrow[2],  w3  = wrow[3];
    float4 w4  = wrow[4],  w5  = wrow[5],  w6  = wrow[6],  w7  = wrow[7];
    float4 w8  = wrow[8],  w9  = wrow[9],  w10 = wrow[10], w11 = wrow[11];
    float4 w12 = wrow[12], w13 = wrow[13], w14 = wrow[14], w15 = wrow[15];

    const float bh = bhh[g * 64 + j];

    const float* xrow = xp + (size_t)b * SS * GG;
    float* hrow = hs + (size_t)b * SS * HH;
    float hcur = 0.f;

    float xg = xrow[g * 64 + j];
    float xn = xrow[128 + j];

#define RL(v, k) __int_as_float(__builtin_amdgcn_readlane(__float_as_int(v), (k)))
#define DOT4(W, i)                                  \
    a0 = fmaf(W.x, RL(hcur, 4*(i) + 0), a0);        \
    a1 = fmaf(W.y, RL(hcur, 4*(i) + 1), a1);        \
    a2 = fmaf(W.z, RL(hcur, 4*(i) + 2), a2);        \
    a3 = fmaf(W.w, RL(hcur, 4*(i) + 3), a3);

    for (int s = 0; s < SS; ++s) {
        const float* nx = xrow + GG;
        float nxg = nx[g * 64 + j];
        float nxn = nx[128 + j];

        float a0 = bh, a1 = 0.f, a2 = 0.f, a3 = 0.f;
        DOT4(w0, 0)   DOT4(w1, 1)   DOT4(w2, 2)   DOT4(w3, 3)
        DOT4(w4, 4)   DOT4(w5, 5)   DOT4(w6, 6)   DOT4(w7, 7)
        DOT4(w8, 8)   DOT4(w9, 9)   DOT4(w10, 10) DOT4(w11, 11)
        DOT4(w12, 12) DOT4(w13, 13) DOT4(w14, 14) DOT4(w15, 15)
        float pre = (a0 + a1) + (a2 + a3);
        gh_s[s & 1][t] = (g < 2) ? (xg + pre) : pre;

        // LDS-only barrier: don't drain vmcnt.
        asm volatile("s_waitcnt lgkmcnt(0)" ::: "memory");
        __builtin_amdgcn_s_barrier();
        asm volatile("" ::: "memory");

        float ghr = gh_s[s & 1][j];
        float ghz = gh_s[s & 1][64 + j];
        float ghn = gh_s[s & 1][128 + j];
        float r = sigmoid_f(ghr);
        float z = sigmoid_f(ghz);
        float n = tanh_f(xn + r * ghn);
        hcur = fmaf(z, hcur - n, n);
        if (g == 0) hrow[j] = hcur;

        xg = nxg; xn = nxn;
        xrow += GG;
        hrow += HH;
    }
#undef DOT4
#undef RL
}

// ---------------------------------------------------------------------------
// FUSED attn_val + scanA (r13). One block per (batch, 16-row tile):
// 256 blocks x 128 threads. Loops 16 rows; Wb row t is re-read per row but
// hits L1 after row 0 (32KB Wb fits L1) -> L2 traffic 256x32KB = 8MB vs
// 4096x32KB = 128MB in the per-row version. Accumulates the tile sums
// (tsum/wsum) inline, eliminating the separate scanA kernel.
// ---------------------------------------------------------------------------
__global__ __launch_bounds__(128) void attn_scanA_kernel(
    const float* __restrict__ h_alpha, const float* __restrict__ h_beta,
    const float* __restrict__ emb, const float* __restrict__ M,
    const float* __restrict__ Wa, const float* __restrict__ ba,
    const float* __restrict__ Wb, const float* __restrict__ bb,
    float* __restrict__ val, float* __restrict__ wj,
    float* __restrict__ tsum, float* __restrict__ wsum)
{
    const int b = blockIdx.x, tt = blockIdx.y;
    const int t = threadIdx.x;       // 0..127
    const int j0 = tt * 16;
    __shared__ float hb_s[HH];
    __shared__ float wj_s;

    const float bbt = bb[t];
    const float4* wrow = (const float4*)&Wb[(size_t)t * HH];

    float ts = 0.f;
    float ws = 0.f;

    for (int jj = 0; jj < 16; ++jj) {
        const int row = b * SS + j0 + jj;
        if (t < 64) {
            hb_s[t] = h_beta[(size_t)row * HH + t];
            float p = h_alpha[(size_t)row * HH + t] * Wa[t];
            #pragma unroll
            for (int off = 32; off > 0; off >>= 1) p += __shfl_down(p, off);
            if (t == 0) {
                float a = __expf(p + ba[0]) * M[row];
                wj_s = a;
                wj[row] = a;
            }
        }
        __syncthreads();

        float acc = bbt;
        #pragma unroll
        for (int k = 0; k < 16; ++k) {
            float4 w4 = wrow[k];
            float4 h4 = *(const float4*)&hb_s[k * 4];
            acc += w4.x*h4.x + w4.y*h4.y + w4.z*h4.z + w4.w*h4.w;
        }
        float v = tanh_f(acc) * emb[(size_t)row * EE + t] * wj_s;
        val[(size_t)row * EE + t] = v;
        ts += v;
        if (t == 0) ws += wj_s;
        __syncthreads();   // hb_s/wj_s reused next row
    }

    tsum[((size_t)(b * TT + tt)) * EE + t] = ts;
    if (t == 0) wsum[b * TT + tt] = ws;
}

// ---------------------------------------------------------------------------
// FUSED scanB + proj (r13). One block per (batch, 16-row tile). Computes the
// suffix-weighted rows into LDS (wtd never touches global memory), then
// projects: out[row][l] = (wtd[row] . Wp[l] + bp[l]) * M[row].
// ---------------------------------------------------------------------------
__global__ __launch_bounds__(128) void scanB_proj_kernel(
    const float* __restrict__ val, const float* __restrict__ wj,
    const float* __restrict__ tsum, const float* __restrict__ wsum,
    const float* __restrict__ Wp, const float* __restrict__ bp,
    const float* __restrict__ M, float* __restrict__ out)
{
    const int b = blockIdx.x, tt = blockIdx.y;
    const int t = threadIdx.x;       // 0..127  (= e for the scan phase)
    const int j0 = tt * 16;

    __shared__ float wtd_s[16][132];
    __shared__ float wp_s[8][132];

    // beyond-tile suffix
    float se = 0.f;
    for (int t2 = tt + 1; t2 < TT; ++t2)
        se += tsum[((size_t)(b * TT + t2)) * EE + t];
    float d = 1e-10f;
    for (int t2 = tt + 1; t2 < TT; ++t2)
        d += wsum[b * TT + t2];

    // in-tile suffix (16 steps), results stay in LDS
    for (int jj = 15; jj >= 0; --jj) {
        size_t idx = ((size_t)(b * SS + j0 + jj)) * EE + t;
        se += val[idx];
        d += wj[b * SS + j0 + jj];
        wtd_s[jj][t] = se / d;
    }

    // stage Wp (8 x 128): 256 float4 total, 2 per thread
    #pragma unroll
    for (int it = 0; it < 2; ++it) {
        int idx = t + it * 128;      // 0..255
        int r = idx >> 5;            // 0..7
        int c = idx & 31;            // 0..31
        *(float4*)&wp_s[r][c * 4] = *(const float4*)&Wp[(size_t)r * EE + c * 4];
    }
    __syncthreads();

    // projection: thread = (row r, output l)
    const int r = t >> 3, l = t & 7;
    float acc = 0.f;
    #pragma unroll
    for (int i = 0; i < 32; ++i) {
        float4 a = *(const float4*)&wtd_s[r][i * 4];
        float4 w = *(const float4*)&wp_s[l][i * 4];
        acc += a.x*w.x + a.y*w.y + a.z*w.z + a.w*w.w;
    }
    const int row = b * SS + j0 + r;
    out[(size_t)row * LL + l] = (acc + bp[l]) * M[row];
}

// ---------------------------------------------------------------------------
// cur_output[b,l] = sum_s all_output[b,s,l] * cur_M[b,s]
// ---------------------------------------------------------------------------
__global__ __launch_bounds__(256) void cur_kernel(
    const float* __restrict__ out_all, const float* __restrict__ curM,
    float* __restrict__ out_cur)
{
    const int b = blockIdx.x;
    const int t = threadIdx.x;
    const int l = t & 7, c = t >> 3;
    float p = 0.f;
    #pragma unroll
    for (int k = 0; k < 8; ++k) {
        int s = c + k * 32;
        p += out_all[((size_t)(b * SS + s)) * LL + l] * curM[b * SS + s];
    }
    __shared__ float red[32][9];
    red[c][l] = p;
    __syncthreads();
    if (t < 8) {
        float sum = 0.f;
        for (int c2 = 0; c2 < 32; ++c2) sum += red[c2][t];
        out_cur[b * LL + t] = sum;
    }
}

// ---------------------------------------------------------------------------
extern "C" void kernel_launch(void* const* d_in, const int* in_sizes, int n_in,
                              void* d_out, int out_size, void* d_ws, size_t ws_size,
                              hipStream_t stream)
{
    const float* X       = (const float*)d_in[0];
    const float* M       = (const float*)d_in[1];
    const float* cur_M   = (const float*)d_in[2];
    const float* W_embed = (const float*)d_in[3];
    const float* b_embed = (const float*)d_in[4];
    const float* Wih_a   = (const float*)d_in[5];
    const float* Whh_a   = (const float*)d_in[6];
    const float* bih_a   = (const float*)d_in[7];
    const float* bhh_a   = (const float*)d_in[8];
    const float* Wih_b   = (const float*)d_in[9];
    const float* Whh_b   = (const float*)d_in[10];
    const float* bih_b   = (const float*)d_in[11];
    const float* bhh_b   = (const float*)d_in[12];
    const float* Wb      = (const float*)d_in[13];
    const float* bb      = (const float*)d_in[14];
    const float* Wa      = (const float*)d_in[15];
    const float* ba      = (const float*)d_in[16];
    const float* Wp      = (const float*)d_in[17];
    const float* bp      = (const float*)d_in[18];
    float* out = (float*)d_out;

    float* ws  = (float*)d_ws;
    float* emb = ws;                          // B*S*E
    float* xpa = emb + (size_t)BB*SS*EE;      // B*S*192
    float* xpb = xpa + (size_t)BB*SS*GG;
    float* ha  = xpb + (size_t)BB*SS*GG;      // B*S*H
    float* hb  = ha  + (size_t)BB*SS*HH;
    float* val = hb  + (size_t)BB*SS*HH;      // B*S*E
    float* wjv = val + (size_t)BB*SS*EE;      // B*S
    float* tsum = wjv + (size_t)BB*SS;        // B*TT*E
    float* wsum = tsum + (size_t)BB*TT*EE;    // B*TT

    const int ROWS = BB * SS;                 // 4096

    gemm_bt<<<dim3(ROWS/32, EE/64), 256, 0, stream>>>(X, W_embed, b_embed, emb, EE, FF);
    gemm_bt_dual<<<dim3(ROWS/32, (GG+63)/64, 2), 256, 0, stream>>>(
        emb, Wih_a, bih_a, xpa, Wih_b, bih_b, xpb, GG, EE);
    gru_kernel<<<32, 192, 0, stream>>>(xpa, xpb, Whh_a, bhh_a, Whh_b, bhh_b, ha, hb);
    attn_scanA_kernel<<<dim3(BB, TT), 128, 0, stream>>>(
        ha, hb, emb, M, Wa, ba, Wb, bb, val, wjv, tsum, wsum);
    scanB_proj_kernel<<<dim3(BB, TT), 128, 0, stream>>>(
        val, wjv, tsum, wsum, Wp, bp, M, out);
    cur_kernel<<<BB, 256, 0, stream>>>(out, cur_M, out + (size_t)BB*SS*LL);
}